// Round 1
// baseline (172.673 us; speedup 1.0000x reference)
//
#include <hip/hip_runtime.h>
#include <math.h>

// Problem constants
#define PP 2048
#define KK 8
#define BB 4
#define NN 16384                 // KK*PP points per cloud
#define CSTRIDE 16392            // KK*(PP+1): stride between coordinate planes
#define BSTRIDE 49176            // 3*CSTRIDE: stride between batches

// Tiling
#define RT 8                     // rows per thread
#define SLICES 32                // col-dimension split
#define COLS_PER_SLICE 512       // NN / SLICES
#define ROWS_PER_BLOCK 2048      // 256 threads * RT

__global__ __launch_bounds__(256) void init_min_kernel(unsigned* __restrict__ mins) {
    int i = blockIdx.x * 256 + threadIdx.x;
    mins[i] = 0x7F7FFFFFu;       // FLT_MAX bit pattern
}

// For each row r of cloud A (one direction), compute min over a 512-col slice of
// cloud B of t_j = 0.5*|b_j|^2 - a.b_j ; final d2 = max(0, |a|^2 + 2*min t).
// Combine slices via atomicMin on non-negative float bits.
__global__ __launch_bounds__(256) void chamfer_dir_kernel(
        const float* __restrict__ Apts, const float* __restrict__ Bpts,
        unsigned* __restrict__ minOut) {
    __shared__ float4 colbuf[COLS_PER_SLICE];
    const int b = blockIdx.z;
    const int tid = threadIdx.x;

    // Stage this block's column slice: (bx, by, bz, 0.5*|b|^2)
    {
        const int cj0 = blockIdx.y * COLS_PER_SLICE;
        for (int j = tid; j < COLS_PER_SLICE; j += 256) {
            int cj = cj0 + j;
            int base = b * BSTRIDE + (cj >> 11) * (PP + 1) + (cj & (PP - 1));
            float bx = Bpts[base];
            float by = Bpts[base + CSTRIDE];
            float bz = Bpts[base + 2 * CSTRIDE];
            colbuf[j] = make_float4(bx, by, bz, 0.5f * (bx * bx + by * by + bz * bz));
        }
    }
    __syncthreads();

    float nax[RT], nay[RT], naz[RT], asq[RT], acc[RT];
    const int r0 = blockIdx.x * ROWS_PER_BLOCK + tid;
#pragma unroll
    for (int i = 0; i < RT; ++i) {
        int r = r0 + i * 256;
        int base = b * BSTRIDE + (r >> 11) * (PP + 1) + (r & (PP - 1));
        float ax = Apts[base];
        float ay = Apts[base + CSTRIDE];
        float az = Apts[base + 2 * CSTRIDE];
        nax[i] = -ax; nay[i] = -ay; naz[i] = -az;
        asq[i] = fmaf(ax, ax, fmaf(ay, ay, az * az));
        acc[i] = 1.0e30f;
    }

    // Inner loop: per col, 1 LDS broadcast read + RT*(3 FMA + 1 min)
#pragma unroll 4
    for (int j = 0; j < COLS_PER_SLICE; ++j) {
        float4 c = colbuf[j];
#pragma unroll
        for (int i = 0; i < RT; ++i) {
            float t = fmaf(nax[i], c.x, fmaf(nay[i], c.y, fmaf(naz[i], c.z, c.w)));
            acc[i] = fminf(acc[i], t);
        }
    }

#pragma unroll
    for (int i = 0; i < RT; ++i) {
        int r = r0 + i * 256;
        float v = fmaxf(fmaf(2.0f, acc[i], asq[i]), 0.0f);   // clamped d2 >= 0
        atomicMin(&minOut[b * NN + r], __float_as_uint(v));
    }
}

__global__ __launch_bounds__(256) void partial_reduce_kernel(
        const unsigned* __restrict__ mins, float* __restrict__ partials) {
    int tid = threadIdx.x;
    float s = 0.f;
    for (int i = blockIdx.x * 256 + tid; i < 2 * BB * NN; i += 128 * 256) {
        s += sqrtf(__uint_as_float(mins[i]));
    }
    __shared__ float red[256];
    red[tid] = s;
    __syncthreads();
    for (int off = 128; off > 0; off >>= 1) {
        if (tid < off) red[tid] += red[tid + off];
        __syncthreads();
    }
    if (tid == 0) partials[blockIdx.x] = red[0];
}

__global__ __launch_bounds__(128) void final_kernel(
        const float* __restrict__ partials,
        const float* __restrict__ pred, const float* __restrict__ tgt,
        float* __restrict__ out) {
    int tid = threadIdx.x;
    // point_cloud_loss = grand_sum / (2 * NN * BB) = / 131072
    float v = partials[tid] * (1.0f / 131072.0f);
    if (tid < 32) {
        int b = tid >> 3, k = tid & 7;
        int idx = b * BSTRIDE + k * (PP + 1) + PP;
        float z = pred[idx];
        float t = tgt[idx] > 0.5f ? 1.0f : 0.0f;
        v += (fmaxf(z, 0.f) - z * t + log1pf(expf(-fabsf(z)))) * (1.0f / 32.0f);
    }
    __shared__ float red[128];
    red[tid] = v;
    __syncthreads();
    for (int off = 64; off > 0; off >>= 1) {
        if (tid < off) red[tid] += red[tid + off];
        __syncthreads();
    }
    if (tid == 0) out[0] = red[0];
}

extern "C" void kernel_launch(void* const* d_in, const int* in_sizes, int n_in,
                              void* d_out, int out_size, void* d_ws, size_t ws_size,
                              hipStream_t stream) {
    const float* pred = (const float*)d_in[0];
    const float* tgt  = (const float*)d_in[1];
    float* out = (float*)d_out;

    unsigned* mins = (unsigned*)d_ws;                                     // 2*BB*NN u32
    float* partials = (float*)((char*)d_ws + 2 * BB * NN * sizeof(unsigned)); // 128 f32

    init_min_kernel<<<2 * BB * NN / 256, 256, 0, stream>>>(mins);
    dim3 grid(NN / ROWS_PER_BLOCK, SLICES, BB);
    chamfer_dir_kernel<<<grid, 256, 0, stream>>>(pred, tgt, mins);            // pred->tgt row mins
    chamfer_dir_kernel<<<grid, 256, 0, stream>>>(tgt, pred, mins + BB * NN);  // tgt->pred row mins
    partial_reduce_kernel<<<128, 256, 0, stream>>>(mins, partials);
    final_kernel<<<1, 128, 0, stream>>>(partials, pred, tgt, out);
}

// Round 2
// 162.863 us; speedup vs baseline: 1.0602x; 1.0602x over previous
//
#include <hip/hip_runtime.h>
#include <math.h>

// Problem constants
#define PP 2048
#define KK 8
#define BB 4
#define NN 16384                 // KK*PP points per cloud
#define CSTRIDE 16392            // KK*(PP+1): stride between coordinate planes
#define BSTRIDE 49176            // 3*CSTRIDE: stride between batches

// Tiling
#define RT 16                    // rows per thread
#define COLS_PER_SLICE 512
#define PAIRS 256                // COLS_PER_SLICE / 2 (cols processed 2 at a time)
#define SLICES 32                // NN / COLS_PER_SLICE
#define ROWS_PER_BLOCK 4096      // 256 threads * RT

typedef float f32x2 __attribute__((ext_vector_type(2)));

// Packed fp32 FMA: d = a*b + c on both 32-bit halves, full rate on CDNA.
__device__ __forceinline__ f32x2 pk_fma(f32x2 a, f32x2 b, f32x2 c) {
    f32x2 d;
    asm("v_pk_fma_f32 %0, %1, %2, %3" : "=v"(d) : "v"(a), "v"(b), "v"(c));
    return d;
}

__global__ __launch_bounds__(256) void init_min_kernel(unsigned* __restrict__ mins) {
    int i = blockIdx.x * 256 + threadIdx.x;
    mins[i] = 0x7F7FFFFFu;       // FLT_MAX bit pattern
}

// Direction kernel: for rows of A, min over a 512-col slice of B of
// t_j = 0.5*|b_j|^2 - a.b_j ; final clamped d2 = max(0, |a|^2 + 2*min t).
// 2 columns per step via v_pk_fma_f32; acc combine via v_min3_f32.
__global__ __launch_bounds__(256, 2) void chamfer_dir_kernel(
        const float* __restrict__ Apts, const float* __restrict__ Bpts,
        unsigned* __restrict__ minOut) {
    __shared__ float4 colA[PAIRS];   // (x0, x1, y0, y1)
    __shared__ float4 colB[PAIRS];   // (z0, z1, w0, w1) with w = 0.5*|b|^2
    const int b = blockIdx.z;
    const int tid = threadIdx.x;

    // Stage column pair 2*tid, 2*tid+1 (pairs never straddle a k-plane: c0 even)
    {
        const int c0 = blockIdx.y * COLS_PER_SLICE + 2 * tid;
        int base = b * BSTRIDE + (c0 >> 11) * (PP + 1) + (c0 & (PP - 1));
        float x0 = Bpts[base],               x1 = Bpts[base + 1];
        float y0 = Bpts[base + CSTRIDE],     y1 = Bpts[base + CSTRIDE + 1];
        float z0 = Bpts[base + 2 * CSTRIDE], z1 = Bpts[base + 2 * CSTRIDE + 1];
        colA[tid] = make_float4(x0, x1, y0, y1);
        colB[tid] = make_float4(z0, z1,
                                0.5f * (x0 * x0 + y0 * y0 + z0 * z0),
                                0.5f * (x1 * x1 + y1 * y1 + z1 * z1));
    }
    __syncthreads();

    f32x2 nax[RT], nay[RT], naz[RT];
    float acc[RT];
    const int r0 = blockIdx.x * ROWS_PER_BLOCK + tid;
#pragma unroll
    for (int i = 0; i < RT; ++i) {
        int r = r0 + i * 256;
        int base = b * BSTRIDE + (r >> 11) * (PP + 1) + (r & (PP - 1));
        float ax = Apts[base];
        float ay = Apts[base + CSTRIDE];
        float az = Apts[base + 2 * CSTRIDE];
        nax[i].x = -ax; nax[i].y = -ax;
        nay[i].x = -ay; nay[i].y = -ay;
        naz[i].x = -az; naz[i].y = -az;
        acc[i] = 1.0e30f;
    }

    // Inner loop: per 2 cols, 2 ds_read_b128 + RT*(3 pk_fma + 1 min3)
#pragma unroll 2
    for (int p = 0; p < PAIRS; ++p) {
        float4 cA = colA[p];
        float4 cB = colB[p];
        f32x2 cxx; cxx.x = cA.x; cxx.y = cA.y;
        f32x2 cyy; cyy.x = cA.z; cyy.y = cA.w;
        f32x2 czz; czz.x = cB.x; czz.y = cB.y;
        f32x2 cww; cww.x = cB.z; cww.y = cB.w;
#pragma unroll
        for (int i = 0; i < RT; ++i) {
            f32x2 t = pk_fma(naz[i], czz, cww);
            t = pk_fma(nay[i], cyy, t);
            t = pk_fma(nax[i], cxx, t);
            acc[i] = fminf(fminf(acc[i], t.x), t.y);   // -> v_min3_f32
        }
    }

#pragma unroll
    for (int i = 0; i < RT; ++i) {
        int r = r0 + i * 256;
        float asq = nax[i].x * nax[i].x + nay[i].x * nay[i].x + naz[i].x * naz[i].x;
        float v = fmaxf(fmaf(2.0f, acc[i], asq), 0.0f);   // clamped d2 >= 0
        atomicMin(&minOut[b * NN + r], __float_as_uint(v));
    }
}

__global__ __launch_bounds__(256) void partial_reduce_kernel(
        const unsigned* __restrict__ mins, float* __restrict__ partials) {
    int tid = threadIdx.x;
    float s = 0.f;
    for (int i = blockIdx.x * 256 + tid; i < 2 * BB * NN; i += 128 * 256) {
        s += sqrtf(__uint_as_float(mins[i]));
    }
    __shared__ float red[256];
    red[tid] = s;
    __syncthreads();
    for (int off = 128; off > 0; off >>= 1) {
        if (tid < off) red[tid] += red[tid + off];
        __syncthreads();
    }
    if (tid == 0) partials[blockIdx.x] = red[0];
}

__global__ __launch_bounds__(128) void final_kernel(
        const float* __restrict__ partials,
        const float* __restrict__ pred, const float* __restrict__ tgt,
        float* __restrict__ out) {
    int tid = threadIdx.x;
    // point_cloud_loss = grand_sum / (2 * NN * BB) = / 131072
    float v = partials[tid] * (1.0f / 131072.0f);
    if (tid < 32) {
        int b = tid >> 3, k = tid & 7;
        int idx = b * BSTRIDE + k * (PP + 1) + PP;
        float z = pred[idx];
        float t = tgt[idx] > 0.5f ? 1.0f : 0.0f;
        v += (fmaxf(z, 0.f) - z * t + log1pf(expf(-fabsf(z)))) * (1.0f / 32.0f);
    }
    __shared__ float red[128];
    red[tid] = v;
    __syncthreads();
    for (int off = 64; off > 0; off >>= 1) {
        if (tid < off) red[tid] += red[tid + off];
        __syncthreads();
    }
    if (tid == 0) out[0] = red[0];
}

extern "C" void kernel_launch(void* const* d_in, const int* in_sizes, int n_in,
                              void* d_out, int out_size, void* d_ws, size_t ws_size,
                              hipStream_t stream) {
    const float* pred = (const float*)d_in[0];
    const float* tgt  = (const float*)d_in[1];
    float* out = (float*)d_out;

    unsigned* mins = (unsigned*)d_ws;                                         // 2*BB*NN u32
    float* partials = (float*)((char*)d_ws + 2 * BB * NN * sizeof(unsigned)); // 128 f32

    init_min_kernel<<<2 * BB * NN / 256, 256, 0, stream>>>(mins);
    dim3 grid(NN / ROWS_PER_BLOCK, SLICES, BB);
    chamfer_dir_kernel<<<grid, 256, 0, stream>>>(pred, tgt, mins);            // pred->tgt
    chamfer_dir_kernel<<<grid, 256, 0, stream>>>(tgt, pred, mins + BB * NN);  // tgt->pred
    partial_reduce_kernel<<<128, 256, 0, stream>>>(mins, partials);
    final_kernel<<<1, 128, 0, stream>>>(partials, pred, tgt, out);
}

// Round 3
// 105.540 us; speedup vs baseline: 1.6361x; 1.5431x over previous
//
#include <hip/hip_runtime.h>
#include <math.h>

// Problem constants
#define PP 2048
#define KK 8
#define BB 4
#define NN 16384                 // KK*PP points per cloud
#define CSTRIDE 16392            // KK*(PP+1): stride between coordinate planes
#define BSTRIDE 49176            // 3*CSTRIDE: stride between batches

// MFMA tiling
#define FRAGS 8                  // a-fragments per wave: 128 rows/wave
#define ROWS_PER_BLOCK 512       // 4 waves * 128
#define ROWBLOCKS 32             // 16384 / 512
#define NSLICES 8                // b-dimension split
#define SLICEPTS 2048            // NN / NSLICES (== PP: one k-plane per slice)
#define CHUNKPTS 512             // staged b-points per chunk
#define TILES 32                 // CHUNKPTS / 16

typedef _Float16 f16;
typedef __attribute__((ext_vector_type(8))) _Float16 f16x8;
typedef __attribute__((ext_vector_type(4))) float f32x4;

__global__ __launch_bounds__(256) void init_min_kernel(unsigned* __restrict__ mins) {
    int i = blockIdx.x * 256 + threadIdx.x;
    mins[i] = 0x7F7FFFFFu;       // FLT_MAX bit pattern
}

// MFMA chamfer direction kernel.
// Computes t = 0.5*|b|^2 - a.b exactly (f16 hi/lo split in spare K-slots);
// d2 = max(0, |a|^2 + 2*min_b t). Combine slices via atomicMin on float bits.
__global__ __launch_bounds__(256, 4) void chamfer_mfma_kernel(
        const float* __restrict__ Apts, const float* __restrict__ Bpts,
        unsigned* __restrict__ minOut) {
    // 4 k-half regions x CHUNKPTS x 16B. Regions 0,1 = b-point records
    // (k-slots 0-7 and 8-15); regions 2,3 stay zero (lanes 32-63 read them).
    __shared__ f16x8 karr[4 * CHUNKPTS];

    const int tid  = threadIdx.x;
    const int lane = tid & 63;
    const int wave = tid >> 6;
    const int col  = lane & 15;       // a-point within fragment / D col
    const int g    = lane >> 4;       // k-half group
    const int b     = blockIdx.z;
    const int slice = blockIdx.y;     // one k-plane of B
    const int rowblock = blockIdx.x;

    // Zero regions 2,3 once (never rewritten).
    for (int i = tid; i < 2 * CHUNKPTS; i += 256) {
        f16x8 z;
#pragma unroll
        for (int j = 0; j < 8; ++j) z[j] = (f16)0.f;
        karr[2 * CHUNKPTS + i] = z;
    }

    // Prologue: per-lane B-operand fragments for this wave's 128 a-points.
    // B-op col vector (K=32): k0-5 = -a_hi,-a_hi ; k6-8 = -a_lo ; k9,10 = 1 ; rest 0.
    f16x8 bop[FRAGS];
    float asq[FRAGS], acc[FRAGS];
    const int rbase = rowblock * ROWS_PER_BLOCK + wave * (FRAGS * 16);
#pragma unroll
    for (int f = 0; f < FRAGS; ++f) {
        int r = rbase + f * 16 + col;
        int abase = b * BSTRIDE + (r >> 11) * (PP + 1) + (r & (PP - 1));
        float ax = Apts[abase];
        float ay = Apts[abase + CSTRIDE];
        float az = Apts[abase + 2 * CSTRIDE];
        asq[f] = fmaf(ax, ax, fmaf(ay, ay, az * az));
        acc[f] = 1.0e30f;
        f16 h0 = (f16)ax, h1 = (f16)ay, h2 = (f16)az;
        f16 l0 = (f16)(ax - (float)h0);
        f16 l1 = (f16)(ay - (float)h1);
        f16 l2 = (f16)(az - (float)h2);
        f16x8 v;
#pragma unroll
        for (int j = 0; j < 8; ++j) v[j] = (f16)0.f;
        if (g == 0) {
            v[0] = -h0; v[1] = -h1; v[2] = -h2;
            v[3] = -h0; v[4] = -h1; v[5] = -h2;
            v[6] = -l0; v[7] = -l1;
        } else if (g == 1) {
            v[0] = -l2; v[1] = (f16)1.f; v[2] = (f16)1.f;
        }
        bop[f] = v;
    }

    const f32x4 C0 = {0.f, 0.f, 0.f, 0.f};
    const int planebase = b * BSTRIDE + slice * (PP + 1);

    for (int c = 0; c < SLICEPTS / CHUNKPTS; ++c) {
        __syncthreads();
        // Stage CHUNKPTS b-points: records for k-slots 0-7 (region 0) and 8-15 (region 1).
        // A-op row vector (K=32): k0-2=b_hi, k3-5=b_lo, k6-8=b_hi, k9=bsq_hi, k10=bsq_lo.
#pragma unroll
        for (int q = 0; q < 2; ++q) {
            int p  = tid + q * 256;
            int gb = planebase + c * CHUNKPTS + p;
            float x = Bpts[gb];
            float y = Bpts[gb + CSTRIDE];
            float z = Bpts[gb + 2 * CSTRIDE];
            f16 h0 = (f16)x, h1 = (f16)y, h2 = (f16)z;
            f16 l0 = (f16)(x - (float)h0);
            f16 l1 = (f16)(y - (float)h1);
            f16 l2 = (f16)(z - (float)h2);
            float bsq = 0.5f * fmaf(x, x, fmaf(y, y, z * z));
            f16 sh = (f16)bsq;
            f16 sl = (f16)(bsq - (float)sh);
            f16x8 lo;
            lo[0] = h0; lo[1] = h1; lo[2] = h2;
            lo[3] = l0; lo[4] = l1; lo[5] = l2;
            lo[6] = h0; lo[7] = h1;
            f16x8 hi;
#pragma unroll
            for (int j = 0; j < 8; ++j) hi[j] = (f16)0.f;
            hi[0] = h2; hi[1] = sh; hi[2] = sl;
            karr[0 * CHUNKPTS + p] = lo;
            karr[1 * CHUNKPTS + p] = hi;
        }
        __syncthreads();

        // Inner loop: per 16-b tile: 1 ds_read_b128 + FRAGS MFMA + 2*FRAGS min3.
        const f16x8* kptr = karr + g * CHUNKPTS + col;
#pragma unroll 4
        for (int t = 0; t < TILES; ++t) {
            f16x8 af = kptr[t * 16];
#pragma unroll
            for (int f = 0; f < FRAGS; ++f) {
                f32x4 d = __builtin_amdgcn_mfma_f32_16x16x32_f16(af, bop[f], C0, 0, 0, 0);
                acc[f] = fminf(fminf(fminf(fminf(acc[f], d[0]), d[1]), d[2]), d[3]);
            }
        }
    }

    // Epilogue: cross-lane min over the 4 k-half groups (b-rows split), then atomic.
#pragma unroll
    for (int f = 0; f < FRAGS; ++f) {
        float m = acc[f];
        m = fminf(m, __shfl_xor(m, 16));
        m = fminf(m, __shfl_xor(m, 32));
        if (lane < 16) {
            float d2 = fmaxf(fmaf(2.0f, m, asq[f]), 0.0f);
            atomicMin(&minOut[b * NN + rbase + f * 16 + col], __float_as_uint(d2));
        }
    }
}

__global__ __launch_bounds__(256) void partial_reduce_kernel(
        const unsigned* __restrict__ mins, float* __restrict__ partials) {
    int tid = threadIdx.x;
    float s = 0.f;
    for (int i = blockIdx.x * 256 + tid; i < 2 * BB * NN; i += 128 * 256) {
        s += sqrtf(__uint_as_float(mins[i]));
    }
    __shared__ float red[256];
    red[tid] = s;
    __syncthreads();
    for (int off = 128; off > 0; off >>= 1) {
        if (tid < off) red[tid] += red[tid + off];
        __syncthreads();
    }
    if (tid == 0) partials[blockIdx.x] = red[0];
}

__global__ __launch_bounds__(128) void final_kernel(
        const float* __restrict__ partials,
        const float* __restrict__ pred, const float* __restrict__ tgt,
        float* __restrict__ out) {
    int tid = threadIdx.x;
    // point_cloud_loss = grand_sum / (2 * NN * BB) = / 131072
    float v = partials[tid] * (1.0f / 131072.0f);
    if (tid < 32) {
        int b = tid >> 3, k = tid & 7;
        int idx = b * BSTRIDE + k * (PP + 1) + PP;
        float z = pred[idx];
        float t = tgt[idx] > 0.5f ? 1.0f : 0.0f;
        v += (fmaxf(z, 0.f) - z * t + log1pf(expf(-fabsf(z)))) * (1.0f / 32.0f);
    }
    __shared__ float red[128];
    red[tid] = v;
    __syncthreads();
    for (int off = 64; off > 0; off >>= 1) {
        if (tid < off) red[tid] += red[tid + off];
        __syncthreads();
    }
    if (tid == 0) out[0] = red[0];
}

extern "C" void kernel_launch(void* const* d_in, const int* in_sizes, int n_in,
                              void* d_out, int out_size, void* d_ws, size_t ws_size,
                              hipStream_t stream) {
    const float* pred = (const float*)d_in[0];
    const float* tgt  = (const float*)d_in[1];
    float* out = (float*)d_out;

    unsigned* mins = (unsigned*)d_ws;                                         // 2*BB*NN u32
    float* partials = (float*)((char*)d_ws + 2 * BB * NN * sizeof(unsigned)); // 128 f32

    init_min_kernel<<<2 * BB * NN / 256, 256, 0, stream>>>(mins);
    dim3 grid(ROWBLOCKS, NSLICES, BB);
    chamfer_mfma_kernel<<<grid, 256, 0, stream>>>(pred, tgt, mins);            // pred->tgt
    chamfer_mfma_kernel<<<grid, 256, 0, stream>>>(tgt, pred, mins + BB * NN);  // tgt->pred
    partial_reduce_kernel<<<128, 256, 0, stream>>>(mins, partials);
    final_kernel<<<1, 128, 0, stream>>>(partials, pred, tgt, out);
}

// Round 4
// 76.317 us; speedup vs baseline: 2.2626x; 1.3829x over previous
//
#include <hip/hip_runtime.h>
#include <math.h>

// Problem constants
#define PP 2048
#define KK 8
#define BB 4
#define NN 16384                 // KK*PP points per cloud
#define CSTRIDE 16392            // KK*(PP+1): stride between coordinate planes
#define BSTRIDE 49176            // 3*CSTRIDE: stride between batches

// MFMA tiling (32x32x16 shape)
#define FRAGS 4                  // a-fragments per wave: 128 rows/wave
#define ROWS_PER_BLOCK 512       // 4 waves * 128
#define ROWBLOCKS 32             // 16384 / 512
#define NSLICES 8                // b-dimension split
#define SLICEPTS 2048            // NN / NSLICES (== PP: one k-plane per slice)
#define CHUNKPTS 512             // staged b-points per chunk
#define TILES 16                 // CHUNKPTS / 32

typedef _Float16 f16;
typedef __attribute__((ext_vector_type(8))) _Float16 f16x8;
typedef __attribute__((ext_vector_type(16))) float f32x16;

__device__ __forceinline__ float min3f(float a, float b, float c) {
    return fminf(fminf(a, b), c);   // -> v_min3_f32
}

__global__ __launch_bounds__(256) void init_min_kernel(unsigned* __restrict__ mins) {
    int i = blockIdx.x * 256 + threadIdx.x;
    mins[i] = 0x7F7FFFFFu;       // FLT_MAX bit pattern
}

// MFMA chamfer direction kernel (32x32x16 f16).
// t = 0.5*|b|^2 - a.b via f16 hi/lo split in 11 K-slots:
//   k0-2: b_hi * -a_hi   k3-5: b_lo * -a_hi   k6-8: b_hi * -a_lo
//   k9: bsq_hi * 1       k10: bsq_lo * 1      k11-15: 0
// d2 = max(0, |a|^2 + 2*min_b t); slices combined via atomicMin on float bits.
__global__ __launch_bounds__(256, 4) void chamfer_mfma_kernel(
        const float* __restrict__ Apts, const float* __restrict__ Bpts,
        unsigned* __restrict__ minOut) {
    // 2 k-group regions x CHUNKPTS x 16B = 16 KB.
    __shared__ f16x8 karr[2 * CHUNKPTS];

    const int tid  = threadIdx.x;
    const int lane = tid & 63;
    const int wave = tid >> 6;
    const int col  = lane & 31;       // a-point col / b-row within tile
    const int g2   = lane >> 5;       // k-group (slots 0-7 vs 8-15)
    const int b     = blockIdx.z;
    const int slice = blockIdx.y;     // one k-plane of B
    const int rowblock = blockIdx.x;

    // Prologue: per-lane B-operand fragments for this wave's 128 a-points.
    f16x8 bop[FRAGS];
    float asq[FRAGS], acc[FRAGS];
    const int rbase = rowblock * ROWS_PER_BLOCK + wave * (FRAGS * 32);
#pragma unroll
    for (int f = 0; f < FRAGS; ++f) {
        int r = rbase + f * 32 + col;
        int abase = b * BSTRIDE + (r >> 11) * (PP + 1) + (r & (PP - 1));
        float ax = Apts[abase];
        float ay = Apts[abase + CSTRIDE];
        float az = Apts[abase + 2 * CSTRIDE];
        asq[f] = fmaf(ax, ax, fmaf(ay, ay, az * az));
        acc[f] = 1.0e30f;
        f16 h0 = (f16)ax, h1 = (f16)ay, h2 = (f16)az;
        f16 l0 = (f16)(ax - (float)h0);
        f16 l1 = (f16)(ay - (float)h1);
        f16 l2 = (f16)(az - (float)h2);
        f16x8 v;
#pragma unroll
        for (int j = 0; j < 8; ++j) v[j] = (f16)0.f;
        if (g2 == 0) {
            v[0] = -h0; v[1] = -h1; v[2] = -h2;
            v[3] = -h0; v[4] = -h1; v[5] = -h2;
            v[6] = -l0; v[7] = -l1;
        } else {
            v[0] = -l2; v[1] = (f16)1.f; v[2] = (f16)1.f;
        }
        bop[f] = v;
    }

    f32x16 Z16;
#pragma unroll
    for (int j = 0; j < 16; ++j) Z16[j] = 0.f;

    const int planebase = b * BSTRIDE + slice * (PP + 1);

    for (int c = 0; c < SLICEPTS / CHUNKPTS; ++c) {
        __syncthreads();
        // Stage CHUNKPTS b-points: A-operand records for k-slots 0-7 and 8-15.
#pragma unroll
        for (int q = 0; q < 2; ++q) {
            int p  = tid + q * 256;
            int gb = planebase + c * CHUNKPTS + p;
            float x = Bpts[gb];
            float y = Bpts[gb + CSTRIDE];
            float z = Bpts[gb + 2 * CSTRIDE];
            f16 h0 = (f16)x, h1 = (f16)y, h2 = (f16)z;
            f16 l0 = (f16)(x - (float)h0);
            f16 l1 = (f16)(y - (float)h1);
            f16 l2 = (f16)(z - (float)h2);
            float bsq = 0.5f * fmaf(x, x, fmaf(y, y, z * z));
            f16 sh = (f16)bsq;
            f16 sl = (f16)(bsq - (float)sh);
            f16x8 lo;
            lo[0] = h0; lo[1] = h1; lo[2] = h2;
            lo[3] = l0; lo[4] = l1; lo[5] = l2;
            lo[6] = h0; lo[7] = h1;
            f16x8 hi;
#pragma unroll
            for (int j = 0; j < 8; ++j) hi[j] = (f16)0.f;
            hi[0] = h2; hi[1] = sh; hi[2] = sl;
            karr[p] = lo;
            karr[CHUNKPTS + p] = hi;
        }
        __syncthreads();

        // Inner loop: per 32-b tile: 1 ds_read_b128 + FRAGS MFMA + FRAGS*8 min3.
        const f16x8* kptr = karr + g2 * CHUNKPTS + col;
#pragma unroll 2
        for (int t = 0; t < TILES; ++t) {
            f16x8 af = kptr[t * 32];
#pragma unroll
            for (int f = 0; f < FRAGS; ++f) {
                f32x16 d = __builtin_amdgcn_mfma_f32_32x32x16_f16(af, bop[f], Z16, 0, 0, 0);
                float m0 = min3f(d[0],  d[1],  d[2]);
                float m1 = min3f(d[3],  d[4],  d[5]);
                float m2 = min3f(d[6],  d[7],  d[8]);
                float m3 = min3f(d[9],  d[10], d[11]);
                float m4 = min3f(d[12], d[13], d[14]);
                float n0 = min3f(m0, m1, m2);
                float n1 = min3f(m3, m4, d[15]);
                acc[f] = min3f(acc[f], n0, n1);
            }
        }
    }

    // Epilogue: b-rows split across lane>>5 only; one shfl then atomic.
#pragma unroll
    for (int f = 0; f < FRAGS; ++f) {
        float m = acc[f];
        m = fminf(m, __shfl_xor(m, 32));
        if (lane < 32) {
            float d2 = fmaxf(fmaf(2.0f, m, asq[f]), 0.0f);
            atomicMin(&minOut[b * NN + rbase + f * 32 + col], __float_as_uint(d2));
        }
    }
}

__global__ __launch_bounds__(256) void partial_reduce_kernel(
        const unsigned* __restrict__ mins, float* __restrict__ partials) {
    int tid = threadIdx.x;
    float s = 0.f;
    for (int i = blockIdx.x * 256 + tid; i < 2 * BB * NN; i += 128 * 256) {
        s += sqrtf(__uint_as_float(mins[i]));
    }
    __shared__ float red[256];
    red[tid] = s;
    __syncthreads();
    for (int off = 128; off > 0; off >>= 1) {
        if (tid < off) red[tid] += red[tid + off];
        __syncthreads();
    }
    if (tid == 0) partials[blockIdx.x] = red[0];
}

__global__ __launch_bounds__(128) void final_kernel(
        const float* __restrict__ partials,
        const float* __restrict__ pred, const float* __restrict__ tgt,
        float* __restrict__ out) {
    int tid = threadIdx.x;
    // point_cloud_loss = grand_sum / (2 * NN * BB) = / 131072
    float v = partials[tid] * (1.0f / 131072.0f);
    if (tid < 32) {
        int b = tid >> 3, k = tid & 7;
        int idx = b * BSTRIDE + k * (PP + 1) + PP;
        float z = pred[idx];
        float t = tgt[idx] > 0.5f ? 1.0f : 0.0f;
        v += (fmaxf(z, 0.f) - z * t + log1pf(expf(-fabsf(z)))) * (1.0f / 32.0f);
    }
    __shared__ float red[128];
    red[tid] = v;
    __syncthreads();
    for (int off = 64; off > 0; off >>= 1) {
        if (tid < off) red[tid] += red[tid + off];
        __syncthreads();
    }
    if (tid == 0) out[0] = red[0];
}

extern "C" void kernel_launch(void* const* d_in, const int* in_sizes, int n_in,
                              void* d_out, int out_size, void* d_ws, size_t ws_size,
                              hipStream_t stream) {
    const float* pred = (const float*)d_in[0];
    const float* tgt  = (const float*)d_in[1];
    float* out = (float*)d_out;

    unsigned* mins = (unsigned*)d_ws;                                         // 2*BB*NN u32
    float* partials = (float*)((char*)d_ws + 2 * BB * NN * sizeof(unsigned)); // 128 f32

    init_min_kernel<<<2 * BB * NN / 256, 256, 0, stream>>>(mins);
    dim3 grid(ROWBLOCKS, NSLICES, BB);
    chamfer_mfma_kernel<<<grid, 256, 0, stream>>>(pred, tgt, mins);            // pred->tgt
    chamfer_mfma_kernel<<<grid, 256, 0, stream>>>(tgt, pred, mins + BB * NN);  // tgt->pred
    partial_reduce_kernel<<<128, 256, 0, stream>>>(mins, partials);
    final_kernel<<<1, 128, 0, stream>>>(partials, pred, tgt, out);
}